// Round 2
// baseline (986.680 us; speedup 1.0000x reference)
//
#include <hip/hip_runtime.h>

#define DEV __device__ __forceinline__

typedef __bf16 bf16x8 __attribute__((ext_vector_type(8)));
typedef float f32x4 __attribute__((ext_vector_type(4)));
typedef unsigned short u16x8 __attribute__((ext_vector_type(8)));
typedef unsigned short u16x2 __attribute__((ext_vector_type(2)));

DEV unsigned short f2bf(float f) {
  unsigned int u = __float_as_uint(f);
  u += 0x7fffu + ((u >> 16) & 1u);   // RNE
  return (unsigned short)(u >> 16);
}
DEV float bf2f(unsigned short h) {
  return __uint_as_float(((unsigned int)h) << 16);
}
DEV void gload16(const void* g, void* l) {
  __builtin_amdgcn_global_load_lds(
      (const __attribute__((address_space(1))) unsigned int*)g,
      (__attribute__((address_space(3))) unsigned int*)l, 16, 0, 0);
}
DEV f32x4 mfma16(bf16x8 a, bf16x8 b, f32x4 c) {
  return __builtin_amdgcn_mfma_f32_16x16x32_bf16(a, b, c, 0, 0, 0);
}

// ---------------- fp32 -> bf16 convert (weights) ----------------
__global__ __launch_bounds__(256) void k_cvt(const float* __restrict__ in,
                                             unsigned short* __restrict__ out, int n8) {
  const int stride = gridDim.x * 256;
  for (int i = blockIdx.x * 256 + threadIdx.x; i < n8; i += stride) {
    const float4* p = (const float4*)(in + (long)i * 8);
    const float4 a = p[0], b = p[1];
    u16x8 o = { f2bf(a.x), f2bf(a.y), f2bf(a.z), f2bf(a.w),
                f2bf(b.x), f2bf(b.y), f2bf(b.z), f2bf(b.w) };
    *(u16x8*)(out + (long)i * 8) = o;
  }
}

// ---------------- RMSNorm: fp32 [rows,2048] -> bf16 ----------------
__global__ __launch_bounds__(256) void k_rmsnorm(const float* __restrict__ x,
                                                 const float* __restrict__ g,
                                                 unsigned short* __restrict__ out) {
  const int row = blockIdx.x;
  const int t = threadIdx.x;
  const float4* xr = (const float4*)(x + (long)row * 2048);
  const float4 a = xr[t * 2], c = xr[t * 2 + 1];
  float ss = a.x * a.x + a.y * a.y + a.z * a.z + a.w * a.w +
             c.x * c.x + c.y * c.y + c.z * c.z + c.w * c.w;
#pragma unroll
  for (int o = 32; o > 0; o >>= 1) ss += __shfl_down(ss, o);
  __shared__ float ws4[4];
  __shared__ float invs;
  if ((t & 63) == 0) ws4[t >> 6] = ss;
  __syncthreads();
  if (t == 0) invs = 1.0f / sqrtf((ws4[0] + ws4[1] + ws4[2] + ws4[3]) * (1.0f / 2048.0f) + 1e-5f);
  __syncthreads();
  const float inv = invs;
  const float4* gr = (const float4*)g;
  const float4 g0 = gr[t * 2], g1v = gr[t * 2 + 1];
  u16x8 o8 = { f2bf(a.x * inv * g0.x),  f2bf(a.y * inv * g0.y),
               f2bf(a.z * inv * g0.z),  f2bf(a.w * inv * g0.w),
               f2bf(c.x * inv * g1v.x), f2bf(c.y * inv * g1v.y),
               f2bf(c.z * inv * g1v.z), f2bf(c.w * inv * g1v.w) };
  *(u16x8*)(out + (long)row * 2048 + t * 8) = o8;
}

// ---------------- GEMM: C[M,N] = A[M,K] * B[N,K]^T (bf16 in, fused epilogues) --------
// EPI 0: store bf16. EPI 1: outF = resid + acc (fp32). EPI 2: outBF = silu(aux)*acc (bf16).
template <int EPI>
__global__ __launch_bounds__(256) void k_gemm_bt(
    const unsigned short* __restrict__ A, const unsigned short* __restrict__ B,
    unsigned short* __restrict__ outBF, float* __restrict__ outF,
    const float* __restrict__ resid, const unsigned short* __restrict__ aux,
    int M, int N, int K) {
  __shared__ __align__(16) unsigned short lds_a[128 * 32];
  __shared__ __align__(16) unsigned short lds_b[128 * 32];
  const int tid = threadIdx.x;
  const int w = tid >> 6, lane = tid & 63;
  const int arow0 = blockIdx.y << 7, bcol0 = blockIdx.x << 7;
  const int wr = (w >> 1) * 64, wc = (w & 1) * 64;

  f32x4 acc[4][4] = {};

  // staging: per wave 2 calls/matrix, rows w*32 + {0,16} + lane/4, swizzled source col
  const int srow = w * 32 + (lane >> 2);
  const int scol = (((lane & 3) ^ ((lane >> 2) & 3)) << 3);
  const unsigned short* gA = A + (long)(arow0 + srow) * K + scol;
  const unsigned short* gB = B + (long)(bcol0 + srow) * K + scol;
  unsigned short* la = &lds_a[w * 1024];
  unsigned short* lb = &lds_b[w * 1024];

  const int fr = lane & 15;
  const int fk = (lane >> 4) << 3;
  const int rk = fk ^ ((fr & 3) << 3);  // swizzled k offset (ushort units)

  for (int k0 = 0; k0 < K; k0 += 32) {
    gload16(gA, la);
    gload16(gA + (size_t)16 * K, la + 512);
    gload16(gB, lb);
    gload16(gB + (size_t)16 * K, lb + 512);
    gA += 32; gB += 32;
    __syncthreads();
    bf16x8 af[4], bfv[4];
#pragma unroll
    for (int m = 0; m < 4; ++m) af[m] = *(const bf16x8*)&lds_a[(wr + m * 16 + fr) * 32 + rk];
#pragma unroll
    for (int n = 0; n < 4; ++n) bfv[n] = *(const bf16x8*)&lds_b[(wc + n * 16 + fr) * 32 + rk];
#pragma unroll
    for (int m = 0; m < 4; ++m)
#pragma unroll
      for (int n = 0; n < 4; ++n)
        acc[m][n] = mfma16(af[m], bfv[n], acc[m][n]);
    __syncthreads();
  }

  const int er = (lane >> 4) << 2;
  const int ec = lane & 15;
#pragma unroll
  for (int m = 0; m < 4; ++m) {
#pragma unroll
    for (int n = 0; n < 4; ++n) {
      const int gr = arow0 + wr + m * 16 + er;
      const int gc = bcol0 + wc + n * 16 + ec;
#pragma unroll
      for (int r = 0; r < 4; ++r) {
        const long idx = (long)(gr + r) * N + gc;
        const float v = acc[m][n][r];
        if constexpr (EPI == 0) {
          outBF[idx] = f2bf(v);
        } else if constexpr (EPI == 1) {
          outF[idx] = resid[idx] + v;
        } else {
          const float x1 = bf2f(aux[idx]);
          const float sl = x1 / (1.0f + __expf(-x1));
          outBF[idx] = f2bf(sl * v);
        }
      }
    }
  }
}

// ---------------- RoPE + head split: qkv[B*S,6144] bf16 -> Qh,Kh [B,H,S,dk] ----------
__global__ __launch_bounds__(256) void k_rope(const unsigned short* __restrict__ qkv,
                                              const int* __restrict__ tp,
                                              unsigned short* __restrict__ Qh,
                                              unsigned short* __restrict__ Kh, int S) {
  const int row = blockIdx.x;  // b*S + s
  const int b = row / S, s = row - b * S;
  const float pos = (float)tp[row];
  for (int p = threadIdx.x; p < 1024; p += 256) {
    const int h = p >> 6, j = p & 63;
    const float ang = pos * __expf((float)j * -0.14391156831212787f);  // theta^(-j/64)
    const float cc = cosf(ang), sn = sinf(ang);
    const long ib = (long)row * 6144 + h * 128 + (j << 1);
    const float q1 = bf2f(qkv[ib]), q2 = bf2f(qkv[ib + 1]);
    const float k1 = bf2f(qkv[ib + 2048]), k2 = bf2f(qkv[ib + 2049]);
    const long ob = (((long)(b * 16 + h)) * S + s) * 128 + (j << 1);
    u16x2 qo = { f2bf(q1 * cc - q2 * sn), f2bf(q2 * cc + q1 * sn) };
    u16x2 ko = { f2bf(k1 * cc - k2 * sn), f2bf(k2 * cc + k1 * sn) };
    *(u16x2*)&Qh[ob] = qo;
    *(u16x2*)&Kh[ob] = ko;
  }
}

// ---------------- V transpose: qkv v-slice -> Vt [B*H, dk=128, S] ----------------
__global__ __launch_bounds__(256) void k_vtrans(const unsigned short* __restrict__ qkv,
                                                unsigned short* __restrict__ Vt, int S) {
  __shared__ __align__(16) unsigned short t[128 * 72];
  const int bh = blockIdx.x, b = bh >> 4, h = bh & 15;
  const int s0 = blockIdx.y << 6;
  const int tid = threadIdx.x;
#pragma unroll
  for (int it = 0; it < 4; ++it) {
    const int sl = it * 16 + (tid >> 4);
    const int c = tid & 15;
    u16x8 v = *(const u16x8*)(qkv + ((long)(b * S + s0 + sl)) * 6144 + 4096 + h * 128 + (c << 3));
#pragma unroll
    for (int jj = 0; jj < 8; ++jj) t[(c * 8 + jj) * 72 + sl] = v[jj];
  }
  __syncthreads();
  const int d = tid >> 1, half = tid & 1;
  unsigned short* dst = Vt + ((long)bh * 128 + d) * S + s0 + half * 32;
  const unsigned short* srcr = &t[d * 72 + half * 32];
#pragma unroll
  for (int u = 0; u < 4; ++u)
    *(u16x8*)(dst + u * 8) = *(const u16x8*)(srcr + u * 8);
}

// ---------------- causal flash attention ----------------
// grid (B*H, S/64); 4 waves x 16 q-rows. K,Vt staged swizzled; online softmax.
__global__ __launch_bounds__(256) void k_attn(const unsigned short* __restrict__ Q,
                                              const unsigned short* __restrict__ Kh,
                                              const unsigned short* __restrict__ Vt,
                                              unsigned short* __restrict__ O, int S) {
  __shared__ __align__(16) unsigned short lds_k[64 * 128];
  __shared__ __align__(16) unsigned short lds_v[128 * 64];
  __shared__ __align__(16) unsigned short lds_p[4 * 16 * 64];
  const int bh = blockIdx.x;
  const int b = bh >> 4, h = bh & 15;
  const int qt = gridDim.y - 1 - blockIdx.y;  // long blocks first
  const int q0 = qt << 6;
  const int tid = threadIdx.x, w = tid >> 6, lane = tid & 63;
  const int fr = lane & 15, g4 = lane >> 4;

  bf16x8 qf[4];
  {
    const unsigned short* qb = Q + ((long)bh * S + q0 + w * 16 + fr) * 128 + (g4 << 3);
#pragma unroll
    for (int kk = 0; kk < 4; ++kk) qf[kk] = *(const bf16x8*)(qb + kk * 32);
  }

  f32x4 accO[8] = {};
  float mrow[4], lrow[4];
#pragma unroll
  for (int r = 0; r < 4; ++r) { mrow[r] = -1e30f; lrow[r] = 0.f; }

  const int k_row = (w << 4) + g4;           // + j*4
  const int k_cb = fr << 4;
  const int v_row = (w << 5) + (lane >> 3);  // + j*8
  const int v_cb = (lane & 7) << 4;
  const long kbase = (long)bh * S * 128;
  const long vbase = (long)bh * 128 * S;

  const int ntile = qt + 1;
  for (int it = 0; it < ntile; ++it) {
    const int kv0 = it << 6;
#pragma unroll
    for (int j = 0; j < 4; ++j) {
      const int kr = k_row + j * 4;
      const int kc = k_cb ^ ((kr & 7) << 4);
      gload16(Kh + kbase + (long)(kv0 + kr) * 128 + (kc >> 1), &lds_k[w * 2048 + j * 512]);
      const int vr = v_row + j * 8;
      const int vc = v_cb ^ ((vr & 7) << 4);
      gload16(Vt + vbase + (long)vr * S + kv0 + (vc >> 1), &lds_v[w * 2048 + j * 512]);
    }
    __syncthreads();

    // S = Q K^T
    f32x4 sc[4] = {};
#pragma unroll
    for (int n = 0; n < 4; ++n) {
      const int krw = n * 16 + fr;
      const int swz = (krw & 7) << 4;
#pragma unroll
      for (int kk = 0; kk < 4; ++kk) {
        const int kb = (kk << 6) + (g4 << 4);
        bf16x8 kf = *(const bf16x8*)&lds_k[krw * 128 + ((kb ^ swz) >> 1)];
        sc[n] = mfma16(qf[kk], kf, sc[n]);
      }
    }

    // online softmax
    const float scl = 0.08838834764831845f;  // 1/sqrt(128)
    float sv[4][4];
    const bool needmask = (kv0 + 63 > q0 + w * 16);
#pragma unroll
    for (int n = 0; n < 4; ++n)
#pragma unroll
      for (int r = 0; r < 4; ++r) {
        float v = sc[n][r] * scl;
        if (needmask) {
          const int qi = q0 + w * 16 + (g4 << 2) + r;
          const int ki = kv0 + n * 16 + fr;
          if (ki > qi) v = -1e30f;
        }
        sv[n][r] = v;
      }
    float corr[4];
#pragma unroll
    for (int r = 0; r < 4; ++r) {
      float tm = fmaxf(fmaxf(sv[0][r], sv[1][r]), fmaxf(sv[2][r], sv[3][r]));
      tm = fmaxf(tm, __shfl_xor(tm, 1));
      tm = fmaxf(tm, __shfl_xor(tm, 2));
      tm = fmaxf(tm, __shfl_xor(tm, 4));
      tm = fmaxf(tm, __shfl_xor(tm, 8));
      const float mn = fmaxf(mrow[r], tm);
      corr[r] = __expf(mrow[r] - mn);
      mrow[r] = mn;
    }
    float rs[4] = {0.f, 0.f, 0.f, 0.f};
#pragma unroll
    for (int n = 0; n < 4; ++n)
#pragma unroll
      for (int r = 0; r < 4; ++r) {
        const float p = __expf(sv[n][r] - mrow[r]);
        rs[r] += p;
        const int pr = (g4 << 2) + r;
        const int pc = (n * 16 + fr) << 1;  // colbyte
        lds_p[(w << 10) + pr * 64 + ((pc ^ ((pr & 7) << 4)) >> 1)] = f2bf(p);
      }
#pragma unroll
    for (int r = 0; r < 4; ++r) {
      float s = rs[r];
      s += __shfl_xor(s, 1);
      s += __shfl_xor(s, 2);
      s += __shfl_xor(s, 4);
      s += __shfl_xor(s, 8);
      lrow[r] = lrow[r] * corr[r] + s;
    }
#pragma unroll
    for (int cb = 0; cb < 8; ++cb)
#pragma unroll
      for (int r = 0; r < 4; ++r) accO[cb][r] *= corr[r];

    // O += P V
#pragma unroll
    for (int kk = 0; kk < 2; ++kk) {
      const int pb = (kk << 6) + (g4 << 4);
      bf16x8 pf = *(const bf16x8*)&lds_p[(w << 10) + fr * 64 + ((pb ^ ((fr & 7) << 4)) >> 1)];
#pragma unroll
      for (int cb = 0; cb < 8; ++cb) {
        const int vrw = cb * 16 + fr;
        bf16x8 vf = *(const bf16x8*)&lds_v[vrw * 64 + ((pb ^ ((vrw & 7) << 4)) >> 1)];
        accO[cb] = mfma16(pf, vf, accO[cb]);
      }
    }
    __syncthreads();
  }

#pragma unroll
  for (int cb = 0; cb < 8; ++cb)
#pragma unroll
    for (int r = 0; r < 4; ++r) {
      const int si = q0 + w * 16 + (g4 << 2) + r;
      const float o = accO[cb][r] / lrow[r];
      O[((long)b * S + si) * 2048 + h * 128 + cb * 16 + fr] = f2bf(o);
    }
}

// ---------------- launch ----------------
// Workspace overlay (176 MB total), liveness enforced by stream order:
//  [  0, 64) MB : Qh/Kh/Vt/O_bf (attn)  -> t_bf (FFN)
//  [ 64,112) MB : qkv_bf               -> x2 (fp32, 32MB) + h2_bf (16MB)
//  [ 96,104) MB : wo_bf (between vtrans and rms2; inside future-h2 slot)
//  [112,144) MB : wqkv_bf(24MB) -> w1_bf -> w2_bf
//  [144,176) MB : h1_bf(16MB)   -> w3_bf
extern "C" void kernel_launch(void* const* d_in, const int* in_sizes, int n_in,
                              void* d_out, int out_size, void* d_ws, size_t ws_size,
                              hipStream_t stream) {
  const float* x    = (const float*)d_in[0];
  const int*   tp   = (const int*)d_in[1];
  const float* Wqkv = (const float*)d_in[2];
  const float* Wo   = (const float*)d_in[3];
  const float* g1   = (const float*)d_in[4];
  const float* g2   = (const float*)d_in[5];
  const float* W1   = (const float*)d_in[6];
  const float* W3   = (const float*)d_in[7];
  const float* W2   = (const float*)d_in[8];
  float* out = (float*)d_out;

  char* ws = (char*)d_ws;
  const size_t MB = 1024 * 1024;
  unsigned short* Qh      = (unsigned short*)(ws + 0 * MB);
  unsigned short* Kh      = (unsigned short*)(ws + 16 * MB);
  unsigned short* Vt      = (unsigned short*)(ws + 32 * MB);
  unsigned short* O_bf    = (unsigned short*)(ws + 48 * MB);
  unsigned short* t_bf    = (unsigned short*)(ws + 0 * MB);    // reuses Qh..O_bf
  unsigned short* qkv_bf  = (unsigned short*)(ws + 64 * MB);
  float*          x2      = (float*)         (ws + 64 * MB);   // reuses qkv
  unsigned short* h2_bf   = (unsigned short*)(ws + 96 * MB);
  unsigned short* wo_bf   = (unsigned short*)(ws + 96 * MB);   // dead before h2 written
  unsigned short* wqkv_bf = (unsigned short*)(ws + 112 * MB);
  unsigned short* w1_bf   = (unsigned short*)(ws + 112 * MB);  // after QKV gemm
  unsigned short* w2_bf   = (unsigned short*)(ws + 112 * MB);  // after FFN gemm1
  unsigned short* h1_bf   = (unsigned short*)(ws + 144 * MB);
  unsigned short* w3_bf   = (unsigned short*)(ws + 144 * MB);  // after QKV gemm

  const int S = 2048;

  // --- attention sublayer ---
  k_cvt<<<1024, 256, 0, stream>>>(Wqkv, wqkv_bf, 12582912 / 8);
  k_rmsnorm<<<4096, 256, 0, stream>>>(x, g1, h1_bf);
  k_gemm_bt<0><<<dim3(48, 32), 256, 0, stream>>>(h1_bf, wqkv_bf, qkv_bf, nullptr, nullptr, nullptr, 4096, 6144, 2048);
  k_rope<<<4096, 256, 0, stream>>>(qkv_bf, tp, Qh, Kh, S);
  k_vtrans<<<dim3(32, 32), 256, 0, stream>>>(qkv_bf, Vt, S);
  k_cvt<<<1024, 256, 0, stream>>>(Wo, wo_bf, 4194304 / 8);       // qkv still live, wo slot separate
  k_cvt<<<1024, 256, 0, stream>>>(W1, w1_bf, 16777216 / 8);      // wqkv dead
  k_cvt<<<1024, 256, 0, stream>>>(W3, w3_bf, 16777216 / 8);      // h1 dead
  k_attn<<<dim3(32, 32), 256, 0, stream>>>(Qh, Kh, Vt, O_bf, S);
  k_gemm_bt<1><<<dim3(16, 32), 256, 0, stream>>>(O_bf, wo_bf, nullptr, x2, x, nullptr, 4096, 2048, 2048);  // qkv dead

  // --- FFN sublayer ---
  k_rmsnorm<<<4096, 256, 0, stream>>>(x2, g2, h2_bf);            // wo dead
  k_gemm_bt<0><<<dim3(64, 32), 256, 0, stream>>>(h2_bf, w1_bf, t_bf, nullptr, nullptr, nullptr, 4096, 8192, 2048);  // Qh..O dead
  k_cvt<<<1024, 256, 0, stream>>>(W2, w2_bf, 16777216 / 8);      // w1 dead
  k_gemm_bt<2><<<dim3(64, 32), 256, 0, stream>>>(h2_bf, w3_bf, t_bf, nullptr, nullptr, t_bf, 4096, 8192, 2048);
  k_gemm_bt<1><<<dim3(16, 32), 256, 0, stream>>>(t_bf, w2_bf, nullptr, out, x2, nullptr, 4096, 2048, 8192);
}

// Round 3
// 830.664 us; speedup vs baseline: 1.1878x; 1.1878x over previous
//
#include <hip/hip_runtime.h>

#define DEV __device__ __forceinline__

typedef __bf16 bf16x8 __attribute__((ext_vector_type(8)));
typedef float f32x4 __attribute__((ext_vector_type(4)));
typedef unsigned short u16x8 __attribute__((ext_vector_type(8)));
typedef unsigned short u16x2 __attribute__((ext_vector_type(2)));

DEV unsigned short f2bf(float f) {
  unsigned int u = __float_as_uint(f);
  u += 0x7fffu + ((u >> 16) & 1u);   // RNE
  return (unsigned short)(u >> 16);
}
DEV float bf2f(unsigned short h) {
  return __uint_as_float(((unsigned int)h) << 16);
}
DEV void gload16(const void* g, void* l) {
  __builtin_amdgcn_global_load_lds(
      (const __attribute__((address_space(1))) unsigned int*)g,
      (__attribute__((address_space(3))) unsigned int*)l, 16, 0, 0);
}
DEV f32x4 mfma16(bf16x8 a, bf16x8 b, f32x4 c) {
  return __builtin_amdgcn_mfma_f32_16x16x32_bf16(a, b, c, 0, 0, 0);
}

// ---------------- fp32 -> bf16 convert (weights) ----------------
__global__ __launch_bounds__(256) void k_cvt(const float* __restrict__ in,
                                             unsigned short* __restrict__ out, int n8) {
  const int stride = gridDim.x * 256;
  for (int i = blockIdx.x * 256 + threadIdx.x; i < n8; i += stride) {
    const float4* p = (const float4*)(in + (long)i * 8);
    const float4 a = p[0], b = p[1];
    u16x8 o = { f2bf(a.x), f2bf(a.y), f2bf(a.z), f2bf(a.w),
                f2bf(b.x), f2bf(b.y), f2bf(b.z), f2bf(b.w) };
    *(u16x8*)(out + (long)i * 8) = o;
  }
}

// ---------------- RMSNorm: fp32 [rows,2048] -> bf16 ----------------
__global__ __launch_bounds__(256) void k_rmsnorm(const float* __restrict__ x,
                                                 const float* __restrict__ g,
                                                 unsigned short* __restrict__ out) {
  const int row = blockIdx.x;
  const int t = threadIdx.x;
  const float4* xr = (const float4*)(x + (long)row * 2048);
  const float4 a = xr[t * 2], c = xr[t * 2 + 1];
  float ss = a.x * a.x + a.y * a.y + a.z * a.z + a.w * a.w +
             c.x * c.x + c.y * c.y + c.z * c.z + c.w * c.w;
#pragma unroll
  for (int o = 32; o > 0; o >>= 1) ss += __shfl_down(ss, o);
  __shared__ float ws4[4];
  __shared__ float invs;
  if ((t & 63) == 0) ws4[t >> 6] = ss;
  __syncthreads();
  if (t == 0) invs = 1.0f / sqrtf((ws4[0] + ws4[1] + ws4[2] + ws4[3]) * (1.0f / 2048.0f) + 1e-5f);
  __syncthreads();
  const float inv = invs;
  const float4* gr = (const float4*)g;
  const float4 g0 = gr[t * 2], g1v = gr[t * 2 + 1];
  u16x8 o8 = { f2bf(a.x * inv * g0.x),  f2bf(a.y * inv * g0.y),
               f2bf(a.z * inv * g0.z),  f2bf(a.w * inv * g0.w),
               f2bf(c.x * inv * g1v.x), f2bf(c.y * inv * g1v.y),
               f2bf(c.z * inv * g1v.z), f2bf(c.w * inv * g1v.w) };
  *(u16x8*)(out + (long)row * 2048 + t * 8) = o8;
}

// ======== 256x256 8-phase GEMM: C[M,N] = A[M,K] * B[N,K]^T (bf16), fused epilogues ====
// EPI 0: store bf16. EPI 1: outF = resid + acc (fp32). EPI 2: outBF = silu(aux)*acc (bf16).
// 8 waves (2Mx4N), BK=64, 2-deep LDS double buffer, counted vmcnt, T2 swizzle, T5 setprio.
template <int EPI>
__global__ __launch_bounds__(512, 2) void k_gemm256(
    const unsigned short* __restrict__ A, const unsigned short* __restrict__ B,
    unsigned short* __restrict__ outBF, float* __restrict__ outF,
    const float* __restrict__ resid, const unsigned short* __restrict__ aux,
    int M, int N, int K) {
  // [buf][mat A/B][half][row 128][col 64] bf16 = 128 KiB
  __shared__ __align__(16) unsigned short lds[2][2][2][128][64];
  const int tid = threadIdx.x;
  const int wid = tid >> 6, lane = tid & 63;
  const int wr = wid >> 2, wc = wid & 3;
  const int fr = lane & 15, g4 = lane >> 4;

  // T1: bijective XCD swizzle (m204)
  const int nwg = gridDim.x;
  int bid = blockIdx.x;
  { int q = nwg >> 3, r = nwg & 7, xcd = bid & 7, lo = bid >> 3;
    bid = (xcd < r ? xcd * (q + 1) : r * (q + 1) + (xcd - r) * q) + lo; }
  const int nxb = N >> 8;
  const int bx = bid % nxb, by = bid / nxb;
  const int arow0 = by << 8, bcol0 = bx << 8;
  const int NT = K >> 6;

  // staging source: thread covers row (tid>>3), 16B granule (tid&7)^(row&7) (T2 pre-swizzle)
  const int srow = tid >> 3;
  const int sg = (tid & 7) ^ (srow & 7);
  const unsigned short* Asrc = A + (long)(arow0 + srow) * K + (sg << 3);
  const unsigned short* Bsrc = B + (long)(bcol0 + srow) * K + (sg << 3);

  // fragment read granule positions (swizzled): row&7 == lane&7 for all frag rows
  const int posk0 = (g4 ^ (lane & 7)) << 3;
  const int posk1 = ((4 + g4) ^ (lane & 7)) << 3;

  f32x4 acc[8][4] = {};
  bf16x8 a[4][2], b0[2][2], b1[2][2];

#define SB   __builtin_amdgcn_s_barrier()
#define SCH  __builtin_amdgcn_sched_barrier(0)
#define LGKM0 asm volatile("s_waitcnt lgkmcnt(0)" ::: "memory")
#define VM2  asm volatile("s_waitcnt vmcnt(2)" ::: "memory")
#define PRIO1 __builtin_amdgcn_s_setprio(1)
#define PRIO0 __builtin_amdgcn_s_setprio(0)
  // stage one half-tile (128 rows x 64 cols) = 2 x global_load_lds call-sites
#define STAGE(SRC, xs, bufi, mat, h)                                            \
  { const unsigned short* s_ = (SRC) + (long)(h) * 128 * K + (long)(xs) * 64;   \
    unsigned short* d_ = &lds[bufi][mat][h][0][0] + wid * 512;                  \
    gload16(s_, d_);                                                            \
    gload16(s_ + (long)64 * K, d_ + 4096); }
#define RD_A(mh)                                                                \
  _Pragma("unroll") for (int m_ = 0; m_ < 4; ++m_) {                            \
    const unsigned short* p_ = baseA + ((mh) * 64 + m_ * 16 + fr) * 64;         \
    a[m_][0] = *(const bf16x8*)(p_ + posk0);                                    \
    a[m_][1] = *(const bf16x8*)(p_ + posk1); }
#define RD_B(arr, nh)                                                           \
  _Pragma("unroll") for (int n_ = 0; n_ < 2; ++n_) {                            \
    const unsigned short* p_ = baseB + ((nh) * 32 + n_ * 16 + fr) * 64;         \
    arr[n_][0] = *(const bf16x8*)(p_ + posk0);                                  \
    arr[n_][1] = *(const bf16x8*)(p_ + posk1); }
#define MM(mh, nh, Bv)                                                          \
  _Pragma("unroll") for (int m_ = 0; m_ < 4; ++m_)                              \
  _Pragma("unroll") for (int n_ = 0; n_ < 2; ++n_) {                            \
    acc[(mh)*4+m_][(nh)*2+n_] = mfma16(a[m_][0], Bv[n_][0], acc[(mh)*4+m_][(nh)*2+n_]); \
    acc[(mh)*4+m_][(nh)*2+n_] = mfma16(a[m_][1], Bv[n_][1], acc[(mh)*4+m_][(nh)*2+n_]); }

  // prologue: tile0 fully + tile1 H0; vmcnt(2) leaves only tile1.H0 in flight
  STAGE(Asrc, 0, 0, 0, 0);
  STAGE(Asrc, 0, 0, 0, 1);
  STAGE(Bsrc, 0, 0, 1, 0);
  STAGE(Bsrc, 0, 0, 1, 1);
  { const int x1p = (NT > 1) ? 1 : 0;
    STAGE(Asrc, x1p, 1, 0, 0); }
  VM2; SCH; SB; SCH;

  for (int t = 0; t < NT; ++t) {
    const unsigned short* baseA = &lds[t & 1][0][wr][0][0];
    const unsigned short* baseB = &lds[t & 1][1][wc >> 1][0][0] + (wc & 1) * 4096;
    const int x1 = (t + 1 < NT) ? t + 1 : NT - 1;   // clamped source tiles
    const int x2 = (t + 2 < NT) ? t + 2 : NT - 1;
    const int bn = (t + 1) & 1, bc = t & 1;

    // P1: quadrant (0,0). reads A(mh0)+B(nh0); stage (t+1).H1 (A half1)
    RD_A(0); RD_B(b0, 0);
    STAGE(Asrc, x1, bn, 0, 1);
    SCH; SB; LGKM0; SCH;
    PRIO1; MM(0, 0, b0); PRIO0;
    SCH; SB; SCH;

    // P2: quadrant (0,1). reads B(nh1); stage (t+1).H2 (B half0)
    RD_B(b1, 1);
    STAGE(Bsrc, x1, bn, 1, 0);
    SCH; SB; LGKM0; SCH;
    PRIO1; MM(0, 1, b1); PRIO0;
    SCH; SB; SCH;

    // P3: quadrant (1,1). reads A(mh1); stage (t+1).H3 (B half1). tile-t LDS reads END here.
    RD_A(1);
    STAGE(Bsrc, x1, bn, 1, 1);
    SCH; SB; LGKM0; SCH;
    PRIO1; MM(1, 1, b1); PRIO0;
    SCH; SB; SCH;

    // P4: quadrant (1,0). no reads; stage (t+2).H0 (A half0, into current buf — reads done).
    STAGE(Asrc, x2, bc, 0, 0);
    SCH; SB; SCH;
    PRIO1; MM(1, 0, b0); PRIO0;
    VM2;   // counted gate: only P4's 2 loads may stay in flight -> tile t+1 fully landed
    SCH; SB; SCH;
  }
#undef SB
#undef SCH
#undef LGKM0
#undef VM2
#undef PRIO1
#undef PRIO0
#undef STAGE
#undef RD_A
#undef RD_B
#undef MM

  // epilogue
  const int er = g4 << 2;
#pragma unroll
  for (int m = 0; m < 8; ++m) {
#pragma unroll
    for (int n = 0; n < 4; ++n) {
      const int grow = arow0 + wr * 128 + m * 16 + er;
      const int gcol = bcol0 + wc * 64 + n * 16 + fr;
#pragma unroll
      for (int r = 0; r < 4; ++r) {
        const long idx = (long)(grow + r) * N + gcol;
        const float v = acc[m][n][r];
        if constexpr (EPI == 0) {
          outBF[idx] = f2bf(v);
        } else if constexpr (EPI == 1) {
          outF[idx] = resid[idx] + v;
        } else {
          const float x1v = bf2f(aux[idx]);
          const float sl = x1v / (1.0f + __expf(-x1v));
          outBF[idx] = f2bf(sl * v);
        }
      }
    }
  }
}

// ---------------- RoPE + head split: qkv[B*S,6144] bf16 -> Qh,Kh [B,H,S,dk] ----------
__global__ __launch_bounds__(256) void k_rope(const unsigned short* __restrict__ qkv,
                                              const int* __restrict__ tp,
                                              unsigned short* __restrict__ Qh,
                                              unsigned short* __restrict__ Kh, int S) {
  const int row = blockIdx.x;  // b*S + s
  const int b = row / S, s = row - b * S;
  const float pos = (float)tp[row];
  for (int p = threadIdx.x; p < 1024; p += 256) {
    const int h = p >> 6, j = p & 63;
    const float ang = pos * __expf((float)j * -0.14391156831212787f);  // theta^(-j/64)
    const float cc = cosf(ang), sn = sinf(ang);
    const long ib = (long)row * 6144 + h * 128 + (j << 1);
    const float q1 = bf2f(qkv[ib]), q2 = bf2f(qkv[ib + 1]);
    const float k1 = bf2f(qkv[ib + 2048]), k2 = bf2f(qkv[ib + 2049]);
    const long ob = (((long)(b * 16 + h)) * S + s) * 128 + (j << 1);
    u16x2 qo = { f2bf(q1 * cc - q2 * sn), f2bf(q2 * cc + q1 * sn) };
    u16x2 ko = { f2bf(k1 * cc - k2 * sn), f2bf(k2 * cc + k1 * sn) };
    *(u16x2*)&Qh[ob] = qo;
    *(u16x2*)&Kh[ob] = ko;
  }
}

// ---------------- V transpose: qkv v-slice -> Vt [B*H, dk=128, S] ----------------
__global__ __launch_bounds__(256) void k_vtrans(const unsigned short* __restrict__ qkv,
                                                unsigned short* __restrict__ Vt, int S) {
  __shared__ __align__(16) unsigned short t[128 * 72];
  const int bh = blockIdx.x, b = bh >> 4, h = bh & 15;
  const int s0 = blockIdx.y << 6;
  const int tid = threadIdx.x;
#pragma unroll
  for (int it = 0; it < 4; ++it) {
    const int sl = it * 16 + (tid >> 4);
    const int c = tid & 15;
    u16x8 v = *(const u16x8*)(qkv + ((long)(b * S + s0 + sl)) * 6144 + 4096 + h * 128 + (c << 3));
#pragma unroll
    for (int jj = 0; jj < 8; ++jj) t[(c * 8 + jj) * 72 + sl] = v[jj];
  }
  __syncthreads();
  const int d = tid >> 1, half = tid & 1;
  unsigned short* dst = Vt + ((long)bh * 128 + d) * S + s0 + half * 32;
  const unsigned short* srcr = &t[d * 72 + half * 32];
#pragma unroll
  for (int u = 0; u < 4; ++u)
    *(u16x8*)(dst + u * 8) = *(const u16x8*)(srcr + u * 8);
}

// ---------------- causal flash attention ----------------
__global__ __launch_bounds__(256) void k_attn(const unsigned short* __restrict__ Q,
                                              const unsigned short* __restrict__ Kh,
                                              const unsigned short* __restrict__ Vt,
                                              unsigned short* __restrict__ O, int S) {
  __shared__ __align__(16) unsigned short lds_k[64 * 128];
  __shared__ __align__(16) unsigned short lds_v[128 * 64];
  __shared__ __align__(16) unsigned short lds_p[4 * 16 * 64];
  const int bh = blockIdx.x;
  const int b = bh >> 4, h = bh & 15;
  const int qt = gridDim.y - 1 - blockIdx.y;  // long blocks first
  const int q0 = qt << 6;
  const int tid = threadIdx.x, w = tid >> 6, lane = tid & 63;
  const int fr = lane & 15, g4 = lane >> 4;

  bf16x8 qf[4];
  {
    const unsigned short* qb = Q + ((long)bh * S + q0 + w * 16 + fr) * 128 + (g4 << 3);
#pragma unroll
    for (int kk = 0; kk < 4; ++kk) qf[kk] = *(const bf16x8*)(qb + kk * 32);
  }

  f32x4 accO[8] = {};
  float mrow[4], lrow[4];
#pragma unroll
  for (int r = 0; r < 4; ++r) { mrow[r] = -1e30f; lrow[r] = 0.f; }

  const int k_row = (w << 4) + g4;
  const int k_cb = fr << 4;
  const int v_row = (w << 5) + (lane >> 3);
  const int v_cb = (lane & 7) << 4;
  const long kbase = (long)bh * S * 128;
  const long vbase = (long)bh * 128 * S;

  const int ntile = qt + 1;
  for (int it = 0; it < ntile; ++it) {
    const int kv0 = it << 6;
#pragma unroll
    for (int j = 0; j < 4; ++j) {
      const int kr = k_row + j * 4;
      const int kc = k_cb ^ ((kr & 7) << 4);
      gload16(Kh + kbase + (long)(kv0 + kr) * 128 + (kc >> 1), &lds_k[w * 2048 + j * 512]);
      const int vr = v_row + j * 8;
      const int vc = v_cb ^ ((vr & 7) << 4);
      gload16(Vt + vbase + (long)vr * S + kv0 + (vc >> 1), &lds_v[w * 2048 + j * 512]);
    }
    __syncthreads();

    f32x4 sc[4] = {};
#pragma unroll
    for (int n = 0; n < 4; ++n) {
      const int krw = n * 16 + fr;
      const int swz = (krw & 7) << 4;
#pragma unroll
      for (int kk = 0; kk < 4; ++kk) {
        const int kb = (kk << 6) + (g4 << 4);
        bf16x8 kf = *(const bf16x8*)&lds_k[krw * 128 + ((kb ^ swz) >> 1)];
        sc[n] = mfma16(qf[kk], kf, sc[n]);
      }
    }

    const float scl = 0.08838834764831845f;  // 1/sqrt(128)
    float sv[4][4];
    const bool needmask = (kv0 + 63 > q0 + w * 16);
#pragma unroll
    for (int n = 0; n < 4; ++n)
#pragma unroll
      for (int r = 0; r < 4; ++r) {
        float v = sc[n][r] * scl;
        if (needmask) {
          const int qi = q0 + w * 16 + (g4 << 2) + r;
          const int ki = kv0 + n * 16 + fr;
          if (ki > qi) v = -1e30f;
        }
        sv[n][r] = v;
      }
    float corr[4];
#pragma unroll
    for (int r = 0; r < 4; ++r) {
      float tm = fmaxf(fmaxf(sv[0][r], sv[1][r]), fmaxf(sv[2][r], sv[3][r]));
      tm = fmaxf(tm, __shfl_xor(tm, 1));
      tm = fmaxf(tm, __shfl_xor(tm, 2));
      tm = fmaxf(tm, __shfl_xor(tm, 4));
      tm = fmaxf(tm, __shfl_xor(tm, 8));
      const float mn = fmaxf(mrow[r], tm);
      corr[r] = __expf(mrow[r] - mn);
      mrow[r] = mn;
    }
    float rs[4] = {0.f, 0.f, 0.f, 0.f};
#pragma unroll
    for (int n = 0; n < 4; ++n)
#pragma unroll
      for (int r = 0; r < 4; ++r) {
        const float p = __expf(sv[n][r] - mrow[r]);
        rs[r] += p;
        const int pr = (g4 << 2) + r;
        const int pc = (n * 16 + fr) << 1;
        lds_p[(w << 10) + pr * 64 + ((pc ^ ((pr & 7) << 4)) >> 1)] = f2bf(p);
      }
#pragma unroll
    for (int r = 0; r < 4; ++r) {
      float s = rs[r];
      s += __shfl_xor(s, 1);
      s += __shfl_xor(s, 2);
      s += __shfl_xor(s, 4);
      s += __shfl_xor(s, 8);
      lrow[r] = lrow[r] * corr[r] + s;
    }
#pragma unroll
    for (int cb = 0; cb < 8; ++cb)
#pragma unroll
      for (int r = 0; r < 4; ++r) accO[cb][r] *= corr[r];

#pragma unroll
    for (int kk = 0; kk < 2; ++kk) {
      const int pb = (kk << 6) + (g4 << 4);
      bf16x8 pf = *(const bf16x8*)&lds_p[(w << 10) + fr * 64 + ((pb ^ ((fr & 7) << 4)) >> 1)];
#pragma unroll
      for (int cb = 0; cb < 8; ++cb) {
        const int vrw = cb * 16 + fr;
        bf16x8 vf = *(const bf16x8*)&lds_v[vrw * 64 + ((pb ^ ((vrw & 7) << 4)) >> 1)];
        accO[cb] = mfma16(pf, vf, accO[cb]);
      }
    }
    __syncthreads();
  }

#pragma unroll
  for (int cb = 0; cb < 8; ++cb)
#pragma unroll
    for (int r = 0; r < 4; ++r) {
      const int si = q0 + w * 16 + (g4 << 2) + r;
      const float o = accO[cb][r] / lrow[r];
      O[((long)b * S + si) * 2048 + h * 128 + cb * 16 + fr] = f2bf(o);
    }
}

// ---------------- launch ----------------
// Workspace overlay (176 MB), liveness by stream order (see R1 notes).
extern "C" void kernel_launch(void* const* d_in, const int* in_sizes, int n_in,
                              void* d_out, int out_size, void* d_ws, size_t ws_size,
                              hipStream_t stream) {
  const float* x    = (const float*)d_in[0];
  const int*   tp   = (const int*)d_in[1];
  const float* Wqkv = (const float*)d_in[2];
  const float* Wo   = (const float*)d_in[3];
  const float* g1   = (const float*)d_in[4];
  const float* g2   = (const float*)d_in[5];
  const float* W1   = (const float*)d_in[6];
  const float* W3   = (const float*)d_in[7];
  const float* W2   = (const float*)d_in[8];
  float* out = (float*)d_out;

  char* ws = (char*)d_ws;
  const size_t MB = 1024 * 1024;
  unsigned short* Qh      = (unsigned short*)(ws + 0 * MB);
  unsigned short* Kh      = (unsigned short*)(ws + 16 * MB);
  unsigned short* Vt      = (unsigned short*)(ws + 32 * MB);
  unsigned short* O_bf    = (unsigned short*)(ws + 48 * MB);
  unsigned short* t_bf    = (unsigned short*)(ws + 0 * MB);    // reuses Qh..O_bf
  unsigned short* qkv_bf  = (unsigned short*)(ws + 64 * MB);
  float*          x2      = (float*)         (ws + 64 * MB);   // reuses qkv
  unsigned short* h2_bf   = (unsigned short*)(ws + 96 * MB);
  unsigned short* wo_bf   = (unsigned short*)(ws + 96 * MB);   // dead before h2 written
  unsigned short* wqkv_bf = (unsigned short*)(ws + 112 * MB);
  unsigned short* w1_bf   = (unsigned short*)(ws + 112 * MB);  // after QKV gemm
  unsigned short* w2_bf   = (unsigned short*)(ws + 112 * MB);  // after FFN gemm1
  unsigned short* h1_bf   = (unsigned short*)(ws + 144 * MB);
  unsigned short* w3_bf   = (unsigned short*)(ws + 144 * MB);  // after QKV gemm

  const int S = 2048;

  // --- attention sublayer ---
  k_cvt<<<1024, 256, 0, stream>>>(Wqkv, wqkv_bf, 12582912 / 8);
  k_rmsnorm<<<4096, 256, 0, stream>>>(x, g1, h1_bf);
  k_gemm256<0><<<dim3(384), 512, 0, stream>>>(h1_bf, wqkv_bf, qkv_bf, nullptr, nullptr, nullptr, 4096, 6144, 2048);
  k_rope<<<4096, 256, 0, stream>>>(qkv_bf, tp, Qh, Kh, S);
  k_vtrans<<<dim3(32, 32), 256, 0, stream>>>(qkv_bf, Vt, S);
  k_cvt<<<1024, 256, 0, stream>>>(Wo, wo_bf, 4194304 / 8);
  k_cvt<<<1024, 256, 0, stream>>>(W1, w1_bf, 16777216 / 8);
  k_cvt<<<1024, 256, 0, stream>>>(W3, w3_bf, 16777216 / 8);
  k_attn<<<dim3(32, 32), 256, 0, stream>>>(Qh, Kh, Vt, O_bf, S);
  k_gemm256<1><<<dim3(128), 512, 0, stream>>>(O_bf, wo_bf, nullptr, x2, x, nullptr, 4096, 2048, 2048);

  // --- FFN sublayer ---
  k_rmsnorm<<<4096, 256, 0, stream>>>(x2, g2, h2_bf);
  k_gemm256<0><<<dim3(512), 512, 0, stream>>>(h2_bf, w1_bf, t_bf, nullptr, nullptr, nullptr, 4096, 8192, 2048);
  k_cvt<<<1024, 256, 0, stream>>>(W2, w2_bf, 16777216 / 8);
  k_gemm256<2><<<dim3(512), 512, 0, stream>>>(h2_bf, w3_bf, t_bf, nullptr, nullptr, t_bf, 4096, 8192, 2048);
  k_gemm256<1><<<dim3(128), 512, 0, stream>>>(t_bf, w2_bf, nullptr, out, x2, nullptr, 4096, 2048, 8192);
}

// Round 4
// 745.444 us; speedup vs baseline: 1.3236x; 1.1143x over previous
//
#include <hip/hip_runtime.h>

#define DEV __device__ __forceinline__

typedef __bf16 bf16x8 __attribute__((ext_vector_type(8)));
typedef float f32x4 __attribute__((ext_vector_type(4)));
typedef unsigned short u16x8 __attribute__((ext_vector_type(8)));
typedef unsigned short u16x2 __attribute__((ext_vector_type(2)));

DEV unsigned short f2bf(float f) {
  unsigned int u = __float_as_uint(f);
  u += 0x7fffu + ((u >> 16) & 1u);   // RNE
  return (unsigned short)(u >> 16);
}
DEV float bf2f(unsigned short h) {
  return __uint_as_float(((unsigned int)h) << 16);
}
DEV void gload16(const void* g, void* l) {
  __builtin_amdgcn_global_load_lds(
      (const __attribute__((address_space(1))) unsigned int*)g,
      (__attribute__((address_space(3))) unsigned int*)l, 16, 0, 0);
}
DEV f32x4 mfma16(bf16x8 a, bf16x8 b, f32x4 c) {
  return __builtin_amdgcn_mfma_f32_16x16x32_bf16(a, b, c, 0, 0, 0);
}

#define SB   __builtin_amdgcn_s_barrier()
#define SCH  __builtin_amdgcn_sched_barrier(0)
#define LGKM0 asm volatile("s_waitcnt lgkmcnt(0)" ::: "memory")
#define PRIO1 __builtin_amdgcn_s_setprio(1)
#define PRIO0 __builtin_amdgcn_s_setprio(0)

// ---------------- fp32 -> bf16 convert (weights) ----------------
__global__ __launch_bounds__(256) void k_cvt(const float* __restrict__ in,
                                             unsigned short* __restrict__ out, int n8) {
  const int stride = gridDim.x * 256;
  for (int i = blockIdx.x * 256 + threadIdx.x; i < n8; i += stride) {
    const float4* p = (const float4*)(in + (long)i * 8);
    const float4 a = p[0], b = p[1];
    u16x8 o = { f2bf(a.x), f2bf(a.y), f2bf(a.z), f2bf(a.w),
                f2bf(b.x), f2bf(b.y), f2bf(b.z), f2bf(b.w) };
    *(u16x8*)(out + (long)i * 8) = o;
  }
}

// ---------------- RMSNorm: fp32 [rows,2048] -> bf16 ----------------
__global__ __launch_bounds__(256) void k_rmsnorm(const float* __restrict__ x,
                                                 const float* __restrict__ g,
                                                 unsigned short* __restrict__ out) {
  const int row = blockIdx.x;
  const int t = threadIdx.x;
  const float4* xr = (const float4*)(x + (long)row * 2048);
  const float4 a = xr[t * 2], c = xr[t * 2 + 1];
  float ss = a.x * a.x + a.y * a.y + a.z * a.z + a.w * a.w +
             c.x * c.x + c.y * c.y + c.z * c.z + c.w * c.w;
#pragma unroll
  for (int o = 32; o > 0; o >>= 1) ss += __shfl_down(ss, o);
  __shared__ float ws4[4];
  __shared__ float invs;
  if ((t & 63) == 0) ws4[t >> 6] = ss;
  __syncthreads();
  if (t == 0) invs = 1.0f / sqrtf((ws4[0] + ws4[1] + ws4[2] + ws4[3]) * (1.0f / 2048.0f) + 1e-5f);
  __syncthreads();
  const float inv = invs;
  const float4* gr = (const float4*)g;
  const float4 g0 = gr[t * 2], g1v = gr[t * 2 + 1];
  u16x8 o8 = { f2bf(a.x * inv * g0.x),  f2bf(a.y * inv * g0.y),
               f2bf(a.z * inv * g0.z),  f2bf(a.w * inv * g0.w),
               f2bf(c.x * inv * g1v.x), f2bf(c.y * inv * g1v.y),
               f2bf(c.z * inv * g1v.z), f2bf(c.w * inv * g1v.w) };
  *(u16x8*)(out + (long)row * 2048 + t * 8) = o8;
}

// ======== 256x256 8-phase GEMM: C[M,N] = A[M,K] * B[N,K]^T (bf16), fused epilogues ====
// EPI 0: store bf16. EPI 1: outF = resid + acc (fp32). EPI 2: outBF = silu(aux)*acc (bf16).
template <int EPI>
__global__ __launch_bounds__(512, 2) void k_gemm256(
    const unsigned short* __restrict__ A, const unsigned short* __restrict__ B,
    unsigned short* __restrict__ outBF, float* __restrict__ outF,
    const float* __restrict__ resid, const unsigned short* __restrict__ aux,
    int M, int N, int K) {
  __shared__ __align__(16) unsigned short lds[2][2][2][128][64];
  const int tid = threadIdx.x;
  const int wid = tid >> 6, lane = tid & 63;
  const int wr = wid >> 2, wc = wid & 3;
  const int fr = lane & 15, g4 = lane >> 4;

  const int nwg = gridDim.x;
  int bid = blockIdx.x;
  { int q = nwg >> 3, r = nwg & 7, xcd = bid & 7, lo = bid >> 3;
    bid = (xcd < r ? xcd * (q + 1) : r * (q + 1) + (xcd - r) * q) + lo; }
  const int nxb = N >> 8;
  const int bx = bid % nxb, by = bid / nxb;
  const int arow0 = by << 8, bcol0 = bx << 8;
  const int NT = K >> 6;

  const int srow = tid >> 3;
  const int sg = (tid & 7) ^ (srow & 7);
  const unsigned short* Asrc = A + (long)(arow0 + srow) * K + (sg << 3);
  const unsigned short* Bsrc = B + (long)(bcol0 + srow) * K + (sg << 3);

  const int posk0 = (g4 ^ (lane & 7)) << 3;
  const int posk1 = ((4 + g4) ^ (lane & 7)) << 3;

  f32x4 acc[8][4] = {};
  bf16x8 a[4][2], b0[2][2], b1[2][2];

#define VM2  asm volatile("s_waitcnt vmcnt(2)" ::: "memory")
#define STAGE(SRC, xs, bufi, mat, h)                                            \
  { const unsigned short* s_ = (SRC) + (long)(h) * 128 * K + (long)(xs) * 64;   \
    unsigned short* d_ = &lds[bufi][mat][h][0][0] + wid * 512;                  \
    gload16(s_, d_);                                                            \
    gload16(s_ + (long)64 * K, d_ + 4096); }
#define RD_A(mh)                                                                \
  _Pragma("unroll") for (int m_ = 0; m_ < 4; ++m_) {                            \
    const unsigned short* p_ = baseA + ((mh) * 64 + m_ * 16 + fr) * 64;         \
    a[m_][0] = *(const bf16x8*)(p_ + posk0);                                    \
    a[m_][1] = *(const bf16x8*)(p_ + posk1); }
#define RD_B(arr, nh)                                                           \
  _Pragma("unroll") for (int n_ = 0; n_ < 2; ++n_) {                            \
    const unsigned short* p_ = baseB + ((nh) * 32 + n_ * 16 + fr) * 64;         \
    arr[n_][0] = *(const bf16x8*)(p_ + posk0);                                  \
    arr[n_][1] = *(const bf16x8*)(p_ + posk1); }
#define MM(mh, nh, Bv)                                                          \
  _Pragma("unroll") for (int m_ = 0; m_ < 4; ++m_)                              \
  _Pragma("unroll") for (int n_ = 0; n_ < 2; ++n_) {                            \
    acc[(mh)*4+m_][(nh)*2+n_] = mfma16(a[m_][0], Bv[n_][0], acc[(mh)*4+m_][(nh)*2+n_]); \
    acc[(mh)*4+m_][(nh)*2+n_] = mfma16(a[m_][1], Bv[n_][1], acc[(mh)*4+m_][(nh)*2+n_]); }

  STAGE(Asrc, 0, 0, 0, 0);
  STAGE(Asrc, 0, 0, 0, 1);
  STAGE(Bsrc, 0, 0, 1, 0);
  STAGE(Bsrc, 0, 0, 1, 1);
  { const int x1p = (NT > 1) ? 1 : 0;
    STAGE(Asrc, x1p, 1, 0, 0); }
  VM2; SCH; SB; SCH;

  for (int t = 0; t < NT; ++t) {
    const unsigned short* baseA = &lds[t & 1][0][wr][0][0];
    const unsigned short* baseB = &lds[t & 1][1][wc >> 1][0][0] + (wc & 1) * 4096;
    const int x1 = (t + 1 < NT) ? t + 1 : NT - 1;
    const int x2 = (t + 2 < NT) ? t + 2 : NT - 1;
    const int bn = (t + 1) & 1, bc = t & 1;

    RD_A(0); RD_B(b0, 0);
    STAGE(Asrc, x1, bn, 0, 1);
    SCH; SB; LGKM0; SCH;
    PRIO1; MM(0, 0, b0); PRIO0;
    SCH; SB; SCH;

    RD_B(b1, 1);
    STAGE(Bsrc, x1, bn, 1, 0);
    SCH; SB; LGKM0; SCH;
    PRIO1; MM(0, 1, b1); PRIO0;
    SCH; SB; SCH;

    RD_A(1);
    STAGE(Bsrc, x1, bn, 1, 1);
    SCH; SB; LGKM0; SCH;
    PRIO1; MM(1, 1, b1); PRIO0;
    SCH; SB; SCH;

    STAGE(Asrc, x2, bc, 0, 0);
    SCH; SB; SCH;
    PRIO1; MM(1, 0, b0); PRIO0;
    VM2;
    SCH; SB; SCH;
  }
#undef VM2
#undef STAGE
#undef RD_A
#undef RD_B
#undef MM

  const int er = g4 << 2;
#pragma unroll
  for (int m = 0; m < 8; ++m) {
#pragma unroll
    for (int n = 0; n < 4; ++n) {
      const int grow = arow0 + wr * 128 + m * 16 + er;
      const int gcol = bcol0 + wc * 64 + n * 16 + fr;
#pragma unroll
      for (int r = 0; r < 4; ++r) {
        const long idx = (long)(grow + r) * N + gcol;
        const float v = acc[m][n][r];
        if constexpr (EPI == 0) {
          outBF[idx] = f2bf(v);
        } else if constexpr (EPI == 1) {
          outF[idx] = resid[idx] + v;
        } else {
          const float x1v = bf2f(aux[idx]);
          const float sl = x1v / (1.0f + __expf(-x1v));
          outBF[idx] = f2bf(sl * v);
        }
      }
    }
  }
}

// ======== 256x128 GEMM for N=2048 (full-machine grid): outF = resid + A*B^T ========
// 8 waves 4Mx2N (per-wave 64x64), BK=64, TRIPLE-buffered LDS (3x48KB), stage t+2,
// 2 phases/K-tile x 16 MFMA, vmcnt(6) counted gate.
__global__ __launch_bounds__(512, 1) void k_gemm_n128(
    const unsigned short* __restrict__ A, const unsigned short* __restrict__ B,
    float* __restrict__ outF, const float* __restrict__ resid, int M, int N, int K) {
  // buf layout: [3][A 256x64 | B 128x64] ushort; A at 0, B at 16384
  __shared__ __align__(16) unsigned short lds[3][384 * 64];
  const int tid = threadIdx.x;
  const int wid = tid >> 6, lane = tid & 63;
  const int wr = wid >> 1, wc = wid & 1;
  const int fr = lane & 15, g4 = lane >> 4;

  const int nwg = gridDim.x;
  int bid = blockIdx.x;
  { int q = nwg >> 3, r = nwg & 7, xcd = bid & 7, lo = bid >> 3;
    bid = (xcd < r ? xcd * (q + 1) : r * (q + 1) + (xcd - r) * q) + lo; }
  const int nxb = N >> 7;
  const int bx = bid % nxb, by = bid / nxb;
  const int arow0 = by << 8, bcol0 = bx << 7;
  const int NT = K >> 6;

  const int srow = tid >> 3;                 // 0..63
  const int sg = (tid & 7) ^ (srow & 7);     // T2 pre-swizzled source granule
  const unsigned short* Asrc = A + (long)(arow0 + srow) * K + (sg << 3);
  const unsigned short* Bsrc = B + (long)(bcol0 + srow) * K + (sg << 3);

  const int posk0 = (g4 ^ (lane & 7)) << 3;
  const int posk1 = ((4 + g4) ^ (lane & 7)) << 3;

  f32x4 acc[4][4] = {};
  bf16x8 a[4][2], bl[2][2], bh[2][2];

#define VM6 asm volatile("s_waitcnt vmcnt(6)" ::: "memory")
  // site: 64 rows x 64 cols = 8KB, one gload16 per thread (wave-uniform dest + lane*16)
#define SITE_A(xs, bufi, s)                                                    \
  gload16(Asrc + (long)((s) * 64) * K + (long)(xs) * 64,                       \
          &lds[bufi][(s) * 4096] + wid * 512);
#define SITE_B(xs, bufi, s)                                                    \
  gload16(Bsrc + (long)((s) * 64) * K + (long)(xs) * 64,                       \
          &lds[bufi][16384 + (s) * 4096] + wid * 512);
#define RDA                                                                    \
  _Pragma("unroll") for (int m_ = 0; m_ < 4; ++m_) {                           \
    const unsigned short* p_ = bufb + (wr * 64 + m_ * 16 + fr) * 64;           \
    a[m_][0] = *(const bf16x8*)(p_ + posk0);                                   \
    a[m_][1] = *(const bf16x8*)(p_ + posk1); }
#define RDB(arr, off)                                                          \
  _Pragma("unroll") for (int n_ = 0; n_ < 2; ++n_) {                           \
    const unsigned short* p_ = bufb + 16384 + (wc * 64 + (off) + n_ * 16 + fr) * 64; \
    arr[n_][0] = *(const bf16x8*)(p_ + posk0);                                 \
    arr[n_][1] = *(const bf16x8*)(p_ + posk1); }
#define MMN(nh, Bv)                                                            \
  _Pragma("unroll") for (int m_ = 0; m_ < 4; ++m_)                             \
  _Pragma("unroll") for (int n_ = 0; n_ < 2; ++n_) {                           \
    acc[m_][(nh)*2+n_] = mfma16(a[m_][0], Bv[n_][0], acc[m_][(nh)*2+n_]);      \
    acc[m_][(nh)*2+n_] = mfma16(a[m_][1], Bv[n_][1], acc[m_][(nh)*2+n_]); }

  // prologue: tiles 0 and 1 fully staged (6 loads each)
  SITE_A(0, 0, 0); SITE_A(0, 0, 1); SITE_A(0, 0, 2); SITE_A(0, 0, 3);
  SITE_B(0, 0, 0); SITE_B(0, 0, 1);
  { const int x1p = (NT > 1) ? 1 : 0;
    SITE_A(x1p, 1, 0); SITE_A(x1p, 1, 1); SITE_A(x1p, 1, 2); SITE_A(x1p, 1, 3);
    SITE_B(x1p, 1, 0); SITE_B(x1p, 1, 1); }
  VM6; SCH; SB; SCH;

  for (int t = 0; t < NT; ++t) {
    const unsigned short* bufb = lds[t % 3];
    const int bn = (t + 2) % 3;
    const int xs = (t + 2 < NT) ? t + 2 : NT - 1;

    // P1: A-frags + B-lo; stage (t+2) sites A0,A1
    RDA; RDB(bl, 0);
    SITE_A(xs, bn, 0); SITE_A(xs, bn, 1);
    SCH; SB; LGKM0; SCH;
    PRIO1; MMN(0, bl); PRIO0;
    SCH; SB; SCH;

    // P2: B-hi; stage (t+2) sites A2,A3,B0,B1
    RDB(bh, 32);
    SITE_A(xs, bn, 2); SITE_A(xs, bn, 3); SITE_B(xs, bn, 0); SITE_B(xs, bn, 1);
    SCH; SB; LGKM0; SCH;
    PRIO1; MMN(1, bh); PRIO0;
    VM6;   // counted: only (t+2)'s 6 loads may remain -> tile t+1 fully landed
    SCH; SB; SCH;
  }
#undef VM6
#undef SITE_A
#undef SITE_B
#undef RDA
#undef RDB
#undef MMN

  const int er = g4 << 2;
#pragma unroll
  for (int m = 0; m < 4; ++m) {
#pragma unroll
    for (int n = 0; n < 4; ++n) {
      const int grow = arow0 + wr * 64 + m * 16 + er;
      const int gcol = bcol0 + wc * 64 + n * 16 + fr;
#pragma unroll
      for (int r = 0; r < 4; ++r) {
        const long idx = (long)(grow + r) * N + gcol;
        outF[idx] = resid[idx] + acc[m][n][r];
      }
    }
  }
}

// ---------------- RoPE + head split: qkv[B*S,6144] bf16 -> Qh,Kh [B,H,S,dk] ----------
__global__ __launch_bounds__(256) void k_rope(const unsigned short* __restrict__ qkv,
                                              const int* __restrict__ tp,
                                              unsigned short* __restrict__ Qh,
                                              unsigned short* __restrict__ Kh, int S) {
  const int row = blockIdx.x;  // b*S + s
  const int b = row / S, s = row - b * S;
  const float pos = (float)tp[row];
  for (int p = threadIdx.x; p < 1024; p += 256) {
    const int h = p >> 6, j = p & 63;
    const float ang = pos * __expf((float)j * -0.14391156831212787f);  // theta^(-j/64)
    const float cc = cosf(ang), sn = sinf(ang);
    const long ib = (long)row * 6144 + h * 128 + (j << 1);
    const float q1 = bf2f(qkv[ib]), q2 = bf2f(qkv[ib + 1]);
    const float k1 = bf2f(qkv[ib + 2048]), k2 = bf2f(qkv[ib + 2049]);
    const long ob = (((long)(b * 16 + h)) * S + s) * 128 + (j << 1);
    u16x2 qo = { f2bf(q1 * cc - q2 * sn), f2bf(q2 * cc + q1 * sn) };
    u16x2 ko = { f2bf(k1 * cc - k2 * sn), f2bf(k2 * cc + k1 * sn) };
    *(u16x2*)&Qh[ob] = qo;
    *(u16x2*)&Kh[ob] = ko;
  }
}

// ---------------- V transpose: qkv v-slice -> Vt [B*H, dk=128, S] ----------------
__global__ __launch_bounds__(256) void k_vtrans(const unsigned short* __restrict__ qkv,
                                                unsigned short* __restrict__ Vt, int S) {
  __shared__ __align__(16) unsigned short t[128 * 72];
  const int bh = blockIdx.x, b = bh >> 4, h = bh & 15;
  const int s0 = blockIdx.y << 6;
  const int tid = threadIdx.x;
#pragma unroll
  for (int it = 0; it < 4; ++it) {
    const int sl = it * 16 + (tid >> 4);
    const int c = tid & 15;
    u16x8 v = *(const u16x8*)(qkv + ((long)(b * S + s0 + sl)) * 6144 + 4096 + h * 128 + (c << 3));
#pragma unroll
    for (int jj = 0; jj < 8; ++jj) t[(c * 8 + jj) * 72 + sl] = v[jj];
  }
  __syncthreads();
  const int d = tid >> 1, half = tid & 1;
  unsigned short* dst = Vt + ((long)bh * 128 + d) * S + s0 + half * 32;
  const unsigned short* srcr = &t[d * 72 + half * 32];
#pragma unroll
  for (int u = 0; u < 4; ++u)
    *(u16x8*)(dst + u * 8) = *(const u16x8*)(srcr + u * 8);
}

// ---------------- causal flash attention ----------------
__global__ __launch_bounds__(256) void k_attn(const unsigned short* __restrict__ Q,
                                              const unsigned short* __restrict__ Kh,
                                              const unsigned short* __restrict__ Vt,
                                              unsigned short* __restrict__ O, int S) {
  __shared__ __align__(16) unsigned short lds_k[64 * 128];
  __shared__ __align__(16) unsigned short lds_v[128 * 64];
  __shared__ __align__(16) unsigned short lds_p[4 * 16 * 64];
  const int bh = blockIdx.x;
  const int b = bh >> 4, h = bh & 15;
  const int qt = gridDim.y - 1 - blockIdx.y;
  const int q0 = qt << 6;
  const int tid = threadIdx.x, w = tid >> 6, lane = tid & 63;
  const int fr = lane & 15, g4 = lane >> 4;

  bf16x8 qf[4];
  {
    const unsigned short* qb = Q + ((long)bh * S + q0 + w * 16 + fr) * 128 + (g4 << 3);
#pragma unroll
    for (int kk = 0; kk < 4; ++kk) qf[kk] = *(const bf16x8*)(qb + kk * 32);
  }

  f32x4 accO[8] = {};
  float mrow[4], lrow[4];
#pragma unroll
  for (int r = 0; r < 4; ++r) { mrow[r] = -1e30f; lrow[r] = 0.f; }

  const int k_row = (w << 4) + g4;
  const int k_cb = fr << 4;
  const int v_row = (w << 5) + (lane >> 3);
  const int v_cb = (lane & 7) << 4;
  const long kbase = (long)bh * S * 128;
  const long vbase = (long)bh * 128 * S;

  const int ntile = qt + 1;
  for (int it = 0; it < ntile; ++it) {
    const int kv0 = it << 6;
#pragma unroll
    for (int j = 0; j < 4; ++j) {
      const int kr = k_row + j * 4;
      const int kc = k_cb ^ ((kr & 7) << 4);
      gload16(Kh + kbase + (long)(kv0 + kr) * 128 + (kc >> 1), &lds_k[w * 2048 + j * 512]);
      const int vr = v_row + j * 8;
      const int vc = v_cb ^ ((vr & 7) << 4);
      gload16(Vt + vbase + (long)vr * S + kv0 + (vc >> 1), &lds_v[w * 2048 + j * 512]);
    }
    __syncthreads();

    f32x4 sc[4] = {};
#pragma unroll
    for (int n = 0; n < 4; ++n) {
      const int krw = n * 16 + fr;
      const int swz = (krw & 7) << 4;
#pragma unroll
      for (int kk = 0; kk < 4; ++kk) {
        const int kb = (kk << 6) + (g4 << 4);
        bf16x8 kf = *(const bf16x8*)&lds_k[krw * 128 + ((kb ^ swz) >> 1)];
        sc[n] = mfma16(qf[kk], kf, sc[n]);
      }
    }

    const float scl = 0.08838834764831845f;
    float sv[4][4];
    const bool needmask = (kv0 + 63 > q0 + w * 16);
#pragma unroll
    for (int n = 0; n < 4; ++n)
#pragma unroll
      for (int r = 0; r < 4; ++r) {
        float v = sc[n][r] * scl;
        if (needmask) {
          const int qi = q0 + w * 16 + (g4 << 2) + r;
          const int ki = kv0 + n * 16 + fr;
          if (ki > qi) v = -1e30f;
        }
        sv[n][r] = v;
      }
    float corr[4];
#pragma unroll
    for (int r = 0; r < 4; ++r) {
      float tm = fmaxf(fmaxf(sv[0][r], sv[1][r]), fmaxf(sv[2][r], sv[3][r]));
      tm = fmaxf(tm, __shfl_xor(tm, 1));
      tm = fmaxf(tm, __shfl_xor(tm, 2));
      tm = fmaxf(tm, __shfl_xor(tm, 4));
      tm = fmaxf(tm, __shfl_xor(tm, 8));
      const float mn = fmaxf(mrow[r], tm);
      corr[r] = __expf(mrow[r] - mn);
      mrow[r] = mn;
    }
    float rs[4] = {0.f, 0.f, 0.f, 0.f};
#pragma unroll
    for (int n = 0; n < 4; ++n)
#pragma unroll
      for (int r = 0; r < 4; ++r) {
        const float p = __expf(sv[n][r] - mrow[r]);
        rs[r] += p;
        const int pr = (g4 << 2) + r;
        const int pc = (n * 16 + fr) << 1;
        lds_p[(w << 10) + pr * 64 + ((pc ^ ((pr & 7) << 4)) >> 1)] = f2bf(p);
      }
#pragma unroll
    for (int r = 0; r < 4; ++r) {
      float s = rs[r];
      s += __shfl_xor(s, 1);
      s += __shfl_xor(s, 2);
      s += __shfl_xor(s, 4);
      s += __shfl_xor(s, 8);
      lrow[r] = lrow[r] * corr[r] + s;
    }
#pragma unroll
    for (int cb = 0; cb < 8; ++cb)
#pragma unroll
      for (int r = 0; r < 4; ++r) accO[cb][r] *= corr[r];

#pragma unroll
    for (int kk = 0; kk < 2; ++kk) {
      const int pb = (kk << 6) + (g4 << 4);
      bf16x8 pf = *(const bf16x8*)&lds_p[(w << 10) + fr * 64 + ((pb ^ ((fr & 7) << 4)) >> 1)];
#pragma unroll
      for (int cb = 0; cb < 8; ++cb) {
        const int vrw = cb * 16 + fr;
        bf16x8 vf = *(const bf16x8*)&lds_v[vrw * 64 + ((pb ^ ((vrw & 7) << 4)) >> 1)];
        accO[cb] = mfma16(pf, vf, accO[cb]);
      }
    }
    __syncthreads();
  }

#pragma unroll
  for (int cb = 0; cb < 8; ++cb)
#pragma unroll
    for (int r = 0; r < 4; ++r) {
      const int si = q0 + w * 16 + (g4 << 2) + r;
      const float o = accO[cb][r] / lrow[r];
      O[((long)b * S + si) * 2048 + h * 128 + cb * 16 + fr] = f2bf(o);
    }
}

// ---------------- launch ----------------
// Workspace overlay (176 MB), liveness by stream order (see R1 notes).
extern "C" void kernel_launch(void* const* d_in, const int* in_sizes, int n_in,
                              void* d_out, int out_size, void* d_ws, size_t ws_size,
                              hipStream_t stream) {
  const float* x    = (const float*)d_in[0];
  const int*   tp   = (const int*)d_in[1];
  const float* Wqkv = (const float*)d_in[2];
  const float* Wo   = (const float*)d_in[3];
  const float* g1   = (const float*)d_in[4];
  const float* g2   = (const float*)d_in[5];
  const float* W1   = (const float*)d_in[6];
  const float* W3   = (const float*)d_in[7];
  const float* W2   = (const float*)d_in[8];
  float* out = (float*)d_out;

  char* ws = (char*)d_ws;
  const size_t MB = 1024 * 1024;
  unsigned short* Qh      = (unsigned short*)(ws + 0 * MB);
  unsigned short* Kh      = (unsigned short*)(ws + 16 * MB);
  unsigned short* Vt      = (unsigned short*)(ws + 32 * MB);
  unsigned short* O_bf    = (unsigned short*)(ws + 48 * MB);
  unsigned short* t_bf    = (unsigned short*)(ws + 0 * MB);    // reuses Qh..O_bf
  unsigned short* qkv_bf  = (unsigned short*)(ws + 64 * MB);
  float*          x2      = (float*)         (ws + 64 * MB);   // reuses qkv
  unsigned short* h2_bf   = (unsigned short*)(ws + 96 * MB);
  unsigned short* wo_bf   = (unsigned short*)(ws + 96 * MB);   // dead before h2 written
  unsigned short* wqkv_bf = (unsigned short*)(ws + 112 * MB);
  unsigned short* w1_bf   = (unsigned short*)(ws + 112 * MB);  // after QKV gemm
  unsigned short* w2_bf   = (unsigned short*)(ws + 112 * MB);  // after FFN gemm1
  unsigned short* h1_bf   = (unsigned short*)(ws + 144 * MB);
  unsigned short* w3_bf   = (unsigned short*)(ws + 144 * MB);  // after QKV gemm

  const int S = 2048;

  // --- attention sublayer ---
  k_cvt<<<1024, 256, 0, stream>>>(Wqkv, wqkv_bf, 12582912 / 8);
  k_rmsnorm<<<4096, 256, 0, stream>>>(x, g1, h1_bf);
  k_gemm256<0><<<dim3(384), 512, 0, stream>>>(h1_bf, wqkv_bf, qkv_bf, nullptr, nullptr, nullptr, 4096, 6144, 2048);
  k_rope<<<4096, 256, 0, stream>>>(qkv_bf, tp, Qh, Kh, S);
  k_vtrans<<<dim3(32, 32), 256, 0, stream>>>(qkv_bf, Vt, S);
  k_cvt<<<1024, 256, 0, stream>>>(Wo, wo_bf, 4194304 / 8);
  k_cvt<<<1024, 256, 0, stream>>>(W1, w1_bf, 16777216 / 8);
  k_cvt<<<1024, 256, 0, stream>>>(W3, w3_bf, 16777216 / 8);
  k_attn<<<dim3(32, 32), 256, 0, stream>>>(Qh, Kh, Vt, O_bf, S);
  k_gemm_n128<<<dim3(256), 512, 0, stream>>>(O_bf, wo_bf, x2, x, 4096, 2048, 2048);

  // --- FFN sublayer ---
  k_rmsnorm<<<4096, 256, 0, stream>>>(x2, g2, h2_bf);
  k_gemm256<0><<<dim3(512), 512, 0, stream>>>(h2_bf, w1_bf, t_bf, nullptr, nullptr, nullptr, 4096, 8192, 2048);
  k_cvt<<<1024, 256, 0, stream>>>(W2, w2_bf, 16777216 / 8);
  k_gemm256<2><<<dim3(512), 512, 0, stream>>>(h2_bf, w3_bf, t_bf, nullptr, nullptr, t_bf, 4096, 8192, 2048);
  k_gemm_n128<<<dim3(256), 512, 0, stream>>>(t_bf, w2_bf, out, x2, 4096, 2048, 8192);
}